// Round 10
// baseline (113.123 us; speedup 1.0000x reference)
//
#include <hip/hip_runtime.h>

typedef unsigned short u16;
typedef unsigned int   u32;
typedef __attribute__((ext_vector_type(8)))  __bf16 bf16x8;
typedef __attribute__((ext_vector_type(16))) float  f32x16;
typedef __attribute__((ext_vector_type(4)))  float  fl4;
typedef __attribute__((ext_vector_type(4)))  u16    u16x4;
typedef __attribute__((ext_vector_type(4)))  u32    u32x4;

#define NB 16
#define NT 2048
#define NC 1024
#define ND 128

// Fragment-order layouts:
//   q/k per batch: [t32 0..63][ds 0..7][lane][8]  (1KB per (t32,ds))
//   v  per batch: [c=t>>4 0..127][dt=d>>5 0..3][lane=(d&31)+32*((t>>3)&1)][j=t&7]
//   wf: [cb 0..11][ks 0..63][lane][8] : W_{cb>>2}[k=ks*16+(lane>>5)*8+j][(cb&3)*32+(lane&31)]

__device__ __forceinline__ u16 f2bf(float f) {
  u32 u = __builtin_bit_cast(u32, f);
  u = (u + 0x7fffu + ((u >> 16) & 1u)) >> 16;
  return (u16)u;
}

__device__ __forceinline__ u32 pk2(float lo, float hi) {
  return (u32)f2bf(lo) | ((u32)f2bf(hi) << 16);
}

// -------------------- Kernel 0: W -> fragment-order wf --------------------
__global__ __launch_bounds__(256) void wprep_k(
    const float* __restrict__ Wq, const float* __restrict__ Wk,
    const float* __restrict__ Wv, u16* __restrict__ wf)
{
  const int cb   = blockIdx.x;          // 0..11
  const int kind = cb >> 2;
  const float* __restrict__ W = (kind == 0) ? Wq : (kind == 1) ? Wk : Wv;
  const int lane = threadIdx.x & 63;
  const int ksq  = threadIdx.x >> 6;    // 0..3
  const int l31 = lane & 31, hi = lane >> 5;
  const int d = (cb & 3) * 32 + l31;
  u16* __restrict__ o = wf + (size_t)cb * 64 * 512;
  #pragma unroll 4
  for (int ii = 0; ii < 16; ++ii) {
    int ks = ksq * 16 + ii;
    int k  = ks * 16 + hi * 8;
    u16x4 p0, p1;
    #pragma unroll
    for (int j = 0; j < 4; ++j) p0[j] = f2bf(W[(size_t)(k + j) * ND + d]);
    #pragma unroll
    for (int j = 0; j < 4; ++j) p1[j] = f2bf(W[(size_t)(k + 4 + j) * ND + d]);
    u16* dst = o + ((size_t)ks * 64 + lane) * 8;
    *(u16x4*)dst = p0;
    *(u16x4*)(dst + 4) = p1;
  }
}

// -------------------- Kernel 1: fused QKV projection (barrier-free inner) ----
// 1024 blocks x 256 thr (4 waves). Block = 32 x-rows, ALL 384 fused cols
// (x read exactly once -> FETCH = 134MB). Whole-K A-tile staged ONCE into
// frag-order LDS (64KB, one barrier total). Inner loop: 64 free-running
// iterations of {1 ds_read_b128 + 3 contiguous B loads + 3 MFMA} with
// depth-4 statically-named B register prefetch (hides L2 latency).
__global__ __launch_bounds__(256, 2) void qkv_fused_k(
    const float* __restrict__ x, const u16* __restrict__ wf,
    u16* __restrict__ qf, u16* __restrict__ kf, u16* __restrict__ vf)
{
  const int tile = blockIdx.x;          // 0..1023
  const int tid  = threadIdx.x;
  const int lane = tid & 63;
  const int wid  = tid >> 6;            // 0..3
  const int l31 = lane & 31, hi = lane >> 5;
  const int m0 = tile * 32;

  __shared__ u16 Af[64 * 512];          // A-frag order: [(ks*64+lane)*8+j], 64KB

  // ---- stage: x[m0..m0+32) x K=1024, f32 -> bf16, frag-order (verified r6) ----
  {
    const int row = tid >> 3;           // 0..31
    const int kb  = (tid & 7) * 4;
    const float* __restrict__ xr = x + (size_t)(m0 + row) * NC;
    #pragma unroll 8
    for (int i = 0; i < 32; ++i) {
      int k = i * 32 + kb;
      fl4 v = *(const fl4*)(xr + k);
      int ks = k >> 4, hik = (k >> 3) & 1, j = k & 7;   // j in {0,4}
      u16x4 pk;
      pk[0] = f2bf(v[0]); pk[1] = f2bf(v[1]); pk[2] = f2bf(v[2]); pk[3] = f2bf(v[3]);
      *(u16x4*)&Af[((size_t)ks * 64 + row + 32 * hik) * 8 + j] = pk;
    }
  }
  __syncthreads();

  // ---- inner: depth-4 B prefetch, no barriers ----
  const u16* __restrict__ wfb = wf + (size_t)wid * 3 * 32768 + (size_t)lane * 8;
  // frag(i, ks) at wfb + i*32768 + ks*512

  bf16x8 pb0[3], pb1[3], pb2[3], pb3[3];
  #define LOADB(dst, ks)                                            \
    { dst[0] = *(const bf16x8*)(wfb + (size_t)(ks) * 512);          \
      dst[1] = *(const bf16x8*)(wfb + 32768 + (size_t)(ks) * 512);  \
      dst[2] = *(const bf16x8*)(wfb + 65536 + (size_t)(ks) * 512); }

  LOADB(pb0, 0); LOADB(pb1, 1); LOADB(pb2, 2); LOADB(pb3, 3);

  f32x16 acc[3] = {};

  #pragma unroll 2
  for (int kq = 0; kq < 16; ++kq) {
    const int ks = kq * 4;
    {
      bf16x8 a = *(const bf16x8*)&Af[(size_t)(ks + 0) * 512 + lane * 8];
      acc[0] = __builtin_amdgcn_mfma_f32_32x32x16_bf16(a, pb0[0], acc[0], 0, 0, 0);
      acc[1] = __builtin_amdgcn_mfma_f32_32x32x16_bf16(a, pb0[1], acc[1], 0, 0, 0);
      acc[2] = __builtin_amdgcn_mfma_f32_32x32x16_bf16(a, pb0[2], acc[2], 0, 0, 0);
      if (kq < 15) LOADB(pb0, ks + 4);
    }
    {
      bf16x8 a = *(const bf16x8*)&Af[(size_t)(ks + 1) * 512 + lane * 8];
      acc[0] = __builtin_amdgcn_mfma_f32_32x32x16_bf16(a, pb1[0], acc[0], 0, 0, 0);
      acc[1] = __builtin_amdgcn_mfma_f32_32x32x16_bf16(a, pb1[1], acc[1], 0, 0, 0);
      acc[2] = __builtin_amdgcn_mfma_f32_32x32x16_bf16(a, pb1[2], acc[2], 0, 0, 0);
      if (kq < 15) LOADB(pb1, ks + 5);
    }
    {
      bf16x8 a = *(const bf16x8*)&Af[(size_t)(ks + 2) * 512 + lane * 8];
      acc[0] = __builtin_amdgcn_mfma_f32_32x32x16_bf16(a, pb2[0], acc[0], 0, 0, 0);
      acc[1] = __builtin_amdgcn_mfma_f32_32x32x16_bf16(a, pb2[1], acc[1], 0, 0, 0);
      acc[2] = __builtin_amdgcn_mfma_f32_32x32x16_bf16(a, pb2[2], acc[2], 0, 0, 0);
      if (kq < 15) LOADB(pb2, ks + 6);
    }
    {
      bf16x8 a = *(const bf16x8*)&Af[(size_t)(ks + 3) * 512 + lane * 8];
      acc[0] = __builtin_amdgcn_mfma_f32_32x32x16_bf16(a, pb3[0], acc[0], 0, 0, 0);
      acc[1] = __builtin_amdgcn_mfma_f32_32x32x16_bf16(a, pb3[1], acc[1], 0, 0, 0);
      acc[2] = __builtin_amdgcn_mfma_f32_32x32x16_bf16(a, pb3[2], acc[2], 0, 0, 0);
      if (kq < 15) LOADB(pb3, ks + 7);
    }
  }
  #undef LOADB

  // ---- epilogue: frag-order q/k/v writes (verified r6) ----
  #pragma unroll
  for (int fn = 0; fn < 3; ++fn) {
    const int colb = wid * 96 + fn * 32;       // wave-uniform
    const int kind = colb >> 7;
    const int d    = (colb + l31) & 127;
    if (kind < 2) {
      u16* __restrict__ o = kind ? kf : qf;
      const float sc = kind ? 1.0f : 0.12752539240377073f; // log2e/sqrt(128)
      const int ds = d >> 4, b3 = (d >> 3) & 1, j = d & 7;
      u16* __restrict__ base = o + ((size_t)tile * 8 + ds) * 512 + 32 * b3 * 8 + j;
      #pragma unroll
      for (int r = 0; r < 16; ++r) {
        int crow = (r & 3) + 8 * (r >> 2) + 4 * hi;
        base[crow * 8] = f2bf(acc[fn][r] * sc);
      }
    } else {
      const int dt = d >> 5;
      #pragma unroll
      for (int g = 0; g < 4; ++g) {
        int c16   = tile * 2 + (g >> 1);
        int lanep = l31 + 32 * (g & 1);
        u16x4 pk;
        #pragma unroll
        for (int jj = 0; jj < 4; ++jj) pk[jj] = f2bf(acc[fn][g * 4 + jj]);
        *(u16x4*)(vf + (((size_t)c16 * 4 + dt) * 64 + lanep) * 8 + 4 * hi) = pk;
      }
    }
  }
}

// -------------------- Kernel 2: flash attention (KV-split x2) --------------------
// 1024 blocks x 2 waves; both waves share one (batch, 32-row q-tile), wave w
// handles kv steps s == w (mod 2). Partials merged via LDS (flash combine).
__global__ __launch_bounds__(128, 2) void attn_fwd_k(
    const u16* __restrict__ qw, const u16* __restrict__ kw,
    const u16* __restrict__ vw, float* __restrict__ out)
{
  const int tid  = threadIdx.x;
  const int lane = tid & 63;
  const int w    = tid >> 6;            // 0/1 split
  const int l31  = lane & 31;
  const int hi   = lane >> 5;

  const int c  = blockIdx.x;
  const int bb = (c >> 6) & 15;
  const int qi = ((c & 63) + ((c >> 8) << 4)) & 63;
  const int q0 = qi * 32;
  const int qrow = q0 + l31;

  const u16* __restrict__ qb = qw + ((size_t)bb * 64 + qi) * 4096;
  const u16* __restrict__ kb = kw + (size_t)bb * 64 * 4096;
  const u16* __restrict__ vb = vw + (size_t)bb * 128 * 2048;

  __shared__ float ofs[64][64];         // [dt*16+r][lane]
  __shared__ float mls[2][64];

  bf16x8 qfr[8];
  #pragma unroll
  for (int s = 0; s < 8; ++s)
    qfr[s] = *(const bf16x8*)(qb + ((size_t)s * 64 + lane) * 8);

  f32x16 of[4] = {};
  float m_run = -__builtin_inff();
  float l_run = 0.f;

  const int nsteps = (qi >> 1) + 1;
  for (int s = w; s < nsteps; s += 2) {
    const int kv0 = s * 64;
    const bool masked = (s == nsteps - 1);

    bf16x8 kf0[8], kf1[8];
    #pragma unroll
    for (int t = 0; t < 8; ++t) {
      kf0[t] = *(const bf16x8*)(kb + (((size_t)(2 * s) * 8 + t) * 64 + lane) * 8);
      kf1[t] = *(const bf16x8*)(kb + (((size_t)(2 * s + 1) * 8 + t) * 64 + lane) * 8);
    }
    f32x16 st0 = {}, st1 = {};
    #pragma unroll
    for (int t = 0; t < 8; ++t) {
      st0 = __builtin_amdgcn_mfma_f32_32x32x16_bf16(kf0[t], qfr[t], st0, 0, 0, 0);
      st1 = __builtin_amdgcn_mfma_f32_32x32x16_bf16(kf1[t], qfr[t], st1, 0, 0, 0);
    }
    bf16x8 vfr[4][4];
    #pragma unroll
    for (int ks = 0; ks < 4; ++ks)
      #pragma unroll
      for (int dt = 0; dt < 4; ++dt)
        vfr[dt][ks] = *(const bf16x8*)(vb + (((size_t)((kv0 >> 4) + ks) * 4 + dt) * 64 + lane) * 8);

    if (masked) {
      #pragma unroll
      for (int r = 0; r < 16; ++r) {
        int crow = (r & 3) + 8 * (r >> 2) + 4 * hi;
        st0[r] = (kv0 + crow      <= qrow) ? st0[r] : -1e30f;
        st1[r] = (kv0 + 32 + crow <= qrow) ? st1[r] : -1e30f;
      }
    }

    float pmax = -1e30f;
    #pragma unroll
    for (int r = 0; r < 16; ++r) pmax = fmaxf(pmax, fmaxf(st0[r], st1[r]));
    pmax = fmaxf(pmax, __shfl_xor(pmax, 32, 64));

    const bool no_rescale = (pmax <= m_run);
    const float m_new = fmaxf(m_run, pmax);
    const float fac = __builtin_amdgcn_exp2f(m_run - m_new);
    float rsum = 0.f;
    #pragma unroll
    for (int r = 0; r < 16; ++r) {
      st0[r] = __builtin_amdgcn_exp2f(st0[r] - m_new);
      st1[r] = __builtin_amdgcn_exp2f(st1[r] - m_new);
      rsum += st0[r] + st1[r];
    }
    rsum += __shfl_xor(rsum, 32, 64);
    l_run = l_run * fac + rsum;
    m_run = m_new;

    if (!__all(no_rescale)) {
      #pragma unroll
      for (int r = 0; r < 16; ++r) {
        float fr = __shfl(fac, (r & 3) + 8 * (r >> 2) + 4 * hi, 64);
        #pragma unroll
        for (int dt = 0; dt < 4; ++dt) of[dt][r] *= fr;
      }
    }

    u32x4 pa[4];
    #pragma unroll
    for (int g = 0; g < 4; ++g) {
      const float* sp = (g < 2) ? (const float*)&st0 : (const float*)&st1;
      const int o8 = (g & 1) * 8;
      u32 a0 = pk2(sp[o8 + 0], sp[o8 + 1]);
      u32 a1 = pk2(sp[o8 + 2], sp[o8 + 3]);
      u32 b0 = pk2(sp[o8 + 4], sp[o8 + 5]);
      u32 b1 = pk2(sp[o8 + 6], sp[o8 + 7]);
      u32 ta0 = __shfl_xor(a0, 32, 64);
      u32 ta1 = __shfl_xor(a1, 32, 64);
      u32 tb0 = __shfl_xor(b0, 32, 64);
      u32 tb1 = __shfl_xor(b1, 32, 64);
      pa[g][0] = hi ? tb0 : a0;
      pa[g][1] = hi ? tb1 : a1;
      pa[g][2] = hi ? b0  : ta0;
      pa[g][3] = hi ? b1  : ta1;
    }

    #pragma unroll
    for (int ks = 0; ks < 4; ++ks) {
      bf16x8 paf = __builtin_bit_cast(bf16x8, pa[ks]);
      #pragma unroll
      for (int dt = 0; dt < 4; ++dt)
        of[dt] = __builtin_amdgcn_mfma_f32_32x32x16_bf16(paf, vfr[dt][ks], of[dt], 0, 0, 0);
    }
  }

  if (w == 1) {
    #pragma unroll
    for (int dt = 0; dt < 4; ++dt)
      #pragma unroll
      for (int r = 0; r < 16; ++r)
        ofs[dt * 16 + r][lane] = of[dt][r];
    mls[0][lane] = m_run;
    mls[1][lane] = l_run;
  }
  __syncthreads();
  if (w == 0) {
    const float m1 = mls[0][l31];
    const float l1 = mls[1][l31];
    const float mt = fmaxf(m_run, m1);
    const float f0 = __builtin_amdgcn_exp2f(m_run - mt);
    const float f1 = __builtin_amdgcn_exp2f(m1 - mt);
    const float lt = l_run * f0 + l1 * f1;
    const float rl = 1.0f / lt;
    #pragma unroll
    for (int r = 0; r < 16; ++r) {
      int crow = (r & 3) + 8 * (r >> 2) + 4 * hi;
      float f0r = __shfl(f0, crow, 64);
      float f1r = __shfl(f1, crow, 64);
      float lr  = __shfl(rl, crow, 64);
      #pragma unroll
      for (int dt = 0; dt < 4; ++dt)
        out[((size_t)(bb * NT + q0 + crow)) * ND + dt * 32 + l31] =
            (of[dt][r] * f0r + ofs[dt * 16 + r][lane] * f1r) * lr;
    }
  }
}

extern "C" void kernel_launch(void* const* d_in, const int* in_sizes, int n_in,
                              void* d_out, int out_size, void* d_ws, size_t ws_size,
                              hipStream_t stream) {
  (void)in_sizes; (void)n_in; (void)out_size; (void)ws_size;
  const float* x  = (const float*)d_in[0];
  const float* Wq = (const float*)d_in[1];
  const float* Wk = (const float*)d_in[2];
  const float* Wv = (const float*)d_in[3];
  float* out = (float*)d_out;

  u16* qws = (u16*)d_ws;                                // frag-order q: 8 MB
  u16* kws = qws + (size_t)NB * NT * ND;                // frag-order k: 8 MB
  u16* vws = kws + (size_t)NB * NT * ND;                // frag-order v: 8 MB
  u16* wfs = vws + (size_t)NB * NT * ND;                // frag-order W: 768 KB

  wprep_k<<<dim3(12), dim3(256), 0, stream>>>(Wq, Wk, Wv, wfs);
  qkv_fused_k<<<dim3(1024), dim3(256), 0, stream>>>(x, wfs, qws, kws, vws);
  attn_fwd_k<<<dim3(1024), dim3(128), 0, stream>>>(qws, kws, vws, out);
}

// Round 11
// 103.789 us; speedup vs baseline: 1.0899x; 1.0899x over previous
//
#include <hip/hip_runtime.h>

typedef unsigned short u16;
typedef unsigned int   u32;
typedef __attribute__((ext_vector_type(8)))  __bf16 bf16x8;
typedef __attribute__((ext_vector_type(16))) float  f32x16;
typedef __attribute__((ext_vector_type(4)))  float  fl4;
typedef __attribute__((ext_vector_type(4)))  u16    u16x4;
typedef __attribute__((ext_vector_type(4)))  u32    u32x4;

#define NB 16
#define NT 2048
#define NC 1024
#define ND 128

// Fragment-order layouts:
//   q/k per batch: [t32 0..63][ds 0..7][lane][8]  (1KB per (t32,ds))
//   v  per batch: [c=t>>4 0..127][dt=d>>5 0..3][lane=(d&31)+32*((t>>3)&1)][j=t&7]
//   wf: [cb 0..11][ks 0..63][lane][8] : W_{cb>>2}[k=ks*16+(lane>>5)*8+j][(cb&3)*32+(lane&31)]

__device__ __forceinline__ u16 f2bf(float f) {
  u32 u = __builtin_bit_cast(u32, f);
  u = (u + 0x7fffu + ((u >> 16) & 1u)) >> 16;
  return (u16)u;
}

__device__ __forceinline__ u32 pk2(float lo, float hi) {
  return (u32)f2bf(lo) | ((u32)f2bf(hi) << 16);
}

// async global->LDS, 16B per lane; gptr per-lane, lptr wave-uniform (HW adds lane*16)
__device__ __forceinline__ void gll16(const u16* g, u16* l) {
  __builtin_amdgcn_global_load_lds(
      (const __attribute__((address_space(1))) void*)g,
      (__attribute__((address_space(3))) void*)l, 16, 0, 0);
}

// -------------------- Kernel 0: W -> fragment-order wf --------------------
__global__ __launch_bounds__(256) void wprep_k(
    const float* __restrict__ Wq, const float* __restrict__ Wk,
    const float* __restrict__ Wv, u16* __restrict__ wf)
{
  const int cb   = blockIdx.x;          // 0..11
  const int kind = cb >> 2;
  const float* __restrict__ W = (kind == 0) ? Wq : (kind == 1) ? Wk : Wv;
  const int lane = threadIdx.x & 63;
  const int ksq  = threadIdx.x >> 6;    // 0..3
  const int l31 = lane & 31, hi = lane >> 5;
  const int d = (cb & 3) * 32 + l31;
  u16* __restrict__ o = wf + (size_t)cb * 64 * 512;
  #pragma unroll 4
  for (int ii = 0; ii < 16; ++ii) {
    int ks = ksq * 16 + ii;
    int k  = ks * 16 + hi * 8;
    u16x4 p0, p1;
    #pragma unroll
    for (int j = 0; j < 4; ++j) p0[j] = f2bf(W[(size_t)(k + j) * ND + d]);
    #pragma unroll
    for (int j = 0; j < 4; ++j) p1[j] = f2bf(W[(size_t)(k + 4 + j) * ND + d]);
    u16* dst = o + ((size_t)ks * 64 + lane) * 8;
    *(u16x4*)dst = p0;
    *(u16x4*)(dst + 4) = p1;
  }
}

// -------------------- Kernel 1: fused QKV projection (m97-style) --------------------
// 1024 blocks = 512 row-tiles(64) x 2 col-halves(192). 256 thr = 4 waves
// (2 row x 2 col), wave tile 32x96, acc = 3 x f32x16 (48 VGPR).
// Per K-step(64): barrier / stage {A: reg->cvt->swizzled LDS, B: 24x
// global_load_lds width16 (linear frag-order)} / barrier / issueA(k+1) /
// compute. 4 blocks/CU co-resident cover the barrier drains (m114/m97).
__global__ __launch_bounds__(256, 4) void qkv_fused_k(
    const float* __restrict__ x, const u16* __restrict__ wf,
    u16* __restrict__ qf, u16* __restrict__ kf, u16* __restrict__ vf)
{
  const int blk = blockIdx.x;           // 0..1023
  const int rt  = blk >> 1;             // 64-row tile
  const int h   = blk & 1;              // 192-col half
  const int tid = threadIdx.x;
  const int lane = tid & 63;
  const int wid  = tid >> 6;            // 0..3
  const int rw = wid & 1, cw = wid >> 1;
  const int l31 = lane & 31, hi = lane >> 5;

  __shared__ u16 As[64 * 64];           // byte = row*128 + (colbyte ^ ((row&7)<<4))
  __shared__ u16 Bs[24 * 512];          // [i 0..5][ks 0..3][lane][8]

  // A staging map: instr i (0..3): row = i*16 + (tid>>4), f32 col = (tid&15)*4
  const int arow = tid >> 4;            // 0..15
  const int ac4  = (tid & 15) * 4;
  const float* __restrict__ xr = x + ((size_t)rt * 64 + arow) * NC + ac4;

  fl4 pA[4];
  auto issueA = [&](int k0) {
    #pragma unroll
    for (int i = 0; i < 4; ++i)
      pA[i] = *(const fl4*)(xr + (size_t)i * 16 * NC + k0);
  };
  auto writeA = [&]() {
    char* b = (char*)As;
    #pragma unroll
    for (int i = 0; i < 4; ++i) {
      int row = i * 16 + arow;
      u16x4 pk;
      pk[0] = f2bf(pA[i][0]); pk[1] = f2bf(pA[i][1]);
      pk[2] = f2bf(pA[i][2]); pk[3] = f2bf(pA[i][3]);
      *(u16x4*)(b + row * 128 + ((ac4 * 2) ^ ((row & 7) << 4))) = pk;
    }
  };

  const u16* __restrict__ wfb = wf + (size_t)(h * 6) * 64 * 512;

  f32x16 acc[3] = {};

  issueA(0);
  for (int k = 0; k < 16; ++k) {
    __syncthreads();                    // (a) prev readers done; pA(k) drained (covered by compute k-1)
    writeA();                           // A(k) -> LDS (swizzled)
    // B(k): 24 x gll, 6 per wave, frag-order (linear both sides)
    #pragma unroll
    for (int j = 0; j < 6; ++j) {
      int c = wid * 6 + j;              // chunk 0..23 = [i=c>>2][ks=c&3]
      gll16(wfb + (((size_t)(c >> 2) * 64 + k * 4 + (c & 3)) * 64 + lane) * 8,
            &Bs[c * 512]);
    }
    __syncthreads();                    // (b) stage visible (gll drained; cross-block covers)
    if (k < 15) issueA((k + 1) * 64);   // drains at next (a) -> full compute of cover
    const char* ab = (const char*)As;
    #pragma unroll
    for (int ks = 0; ks < 4; ++ks) {
      int row = rw * 32 + l31;
      bf16x8 a = *(const bf16x8*)(ab + row * 128 + ((ks * 32 + hi * 16) ^ ((row & 7) << 4)));
      #pragma unroll
      for (int cb = 0; cb < 3; ++cb) {
        bf16x8 b = *(const bf16x8*)&Bs[((cw * 3 + cb) * 4 + ks) * 512 + lane * 8];
        acc[cb] = __builtin_amdgcn_mfma_f32_32x32x16_bf16(a, b, acc[cb], 0, 0, 0);
      }
    }
  }

  // ---- epilogue: frag-order q/k/v writes (verified r6/r9) ----
  const int t32 = rt * 2 + rw;
  #pragma unroll
  for (int cb = 0; cb < 3; ++cb) {
    const int colb = h * 192 + cw * 96 + cb * 32;  // wave-uniform
    const int kind = colb >> 7;
    const int d    = (colb & 127) + l31;
    if (kind < 2) {
      u16* __restrict__ o = kind ? kf : qf;
      const float sc = kind ? 1.0f : 0.12752539240377073f; // log2e/sqrt(128)
      const int ds = d >> 4, b3 = (d >> 3) & 1, j = d & 7;
      u16* __restrict__ base = o + ((size_t)t32 * 8 + ds) * 512 + 32 * b3 * 8 + j;
      #pragma unroll
      for (int r = 0; r < 16; ++r) {
        int crow = (r & 3) + 8 * (r >> 2) + 4 * hi;
        base[crow * 8] = f2bf(acc[cb][r] * sc);
      }
    } else {
      const int dt = (d & 127) >> 5;
      #pragma unroll
      for (int g = 0; g < 4; ++g) {
        int c16   = t32 * 2 + (g >> 1);
        int lanep = l31 + 32 * (g & 1);
        u16x4 pk;
        #pragma unroll
        for (int jj = 0; jj < 4; ++jj) pk[jj] = f2bf(acc[cb][g * 4 + jj]);
        *(u16x4*)(vf + (((size_t)c16 * 4 + dt) * 64 + lanep) * 8 + 4 * hi) = pk;
      }
    }
  }
}

// -------------------- Kernel 2: flash attention (KV-split x2) --------------------
__global__ __launch_bounds__(128, 2) void attn_fwd_k(
    const u16* __restrict__ qw, const u16* __restrict__ kw,
    const u16* __restrict__ vw, float* __restrict__ out)
{
  const int tid  = threadIdx.x;
  const int lane = tid & 63;
  const int w    = tid >> 6;            // 0/1 split
  const int l31  = lane & 31;
  const int hi   = lane >> 5;

  const int c  = blockIdx.x;
  const int bb = (c >> 6) & 15;
  const int qi = ((c & 63) + ((c >> 8) << 4)) & 63;
  const int q0 = qi * 32;
  const int qrow = q0 + l31;

  const u16* __restrict__ qb = qw + ((size_t)bb * 64 + qi) * 4096;
  const u16* __restrict__ kb = kw + (size_t)bb * 64 * 4096;
  const u16* __restrict__ vb = vw + (size_t)bb * 128 * 2048;

  __shared__ float ofs[64][64];         // [dt*16+r][lane]
  __shared__ float mls[2][64];

  bf16x8 qfr[8];
  #pragma unroll
  for (int s = 0; s < 8; ++s)
    qfr[s] = *(const bf16x8*)(qb + ((size_t)s * 64 + lane) * 8);

  f32x16 of[4] = {};
  float m_run = -__builtin_inff();
  float l_run = 0.f;

  const int nsteps = (qi >> 1) + 1;
  for (int s = w; s < nsteps; s += 2) {
    const int kv0 = s * 64;
    const bool masked = (s == nsteps - 1);

    bf16x8 kf0[8], kf1[8];
    #pragma unroll
    for (int t = 0; t < 8; ++t) {
      kf0[t] = *(const bf16x8*)(kb + (((size_t)(2 * s) * 8 + t) * 64 + lane) * 8);
      kf1[t] = *(const bf16x8*)(kb + (((size_t)(2 * s + 1) * 8 + t) * 64 + lane) * 8);
    }
    f32x16 st0 = {}, st1 = {};
    #pragma unroll
    for (int t = 0; t < 8; ++t) {
      st0 = __builtin_amdgcn_mfma_f32_32x32x16_bf16(kf0[t], qfr[t], st0, 0, 0, 0);
      st1 = __builtin_amdgcn_mfma_f32_32x32x16_bf16(kf1[t], qfr[t], st1, 0, 0, 0);
    }
    bf16x8 vfr[4][4];
    #pragma unroll
    for (int ks = 0; ks < 4; ++ks)
      #pragma unroll
      for (int dt = 0; dt < 4; ++dt)
        vfr[dt][ks] = *(const bf16x8*)(vb + (((size_t)((kv0 >> 4) + ks) * 4 + dt) * 64 + lane) * 8);

    if (masked) {
      #pragma unroll
      for (int r = 0; r < 16; ++r) {
        int crow = (r & 3) + 8 * (r >> 2) + 4 * hi;
        st0[r] = (kv0 + crow      <= qrow) ? st0[r] : -1e30f;
        st1[r] = (kv0 + 32 + crow <= qrow) ? st1[r] : -1e30f;
      }
    }

    float pmax = -1e30f;
    #pragma unroll
    for (int r = 0; r < 16; ++r) pmax = fmaxf(pmax, fmaxf(st0[r], st1[r]));
    pmax = fmaxf(pmax, __shfl_xor(pmax, 32, 64));

    const bool no_rescale = (pmax <= m_run);
    const float m_new = fmaxf(m_run, pmax);
    const float fac = __builtin_amdgcn_exp2f(m_run - m_new);
    float rsum = 0.f;
    #pragma unroll
    for (int r = 0; r < 16; ++r) {
      st0[r] = __builtin_amdgcn_exp2f(st0[r] - m_new);
      st1[r] = __builtin_amdgcn_exp2f(st1[r] - m_new);
      rsum += st0[r] + st1[r];
    }
    rsum += __shfl_xor(rsum, 32, 64);
    l_run = l_run * fac + rsum;
    m_run = m_new;

    if (!__all(no_rescale)) {
      #pragma unroll
      for (int r = 0; r < 16; ++r) {
        float fr = __shfl(fac, (r & 3) + 8 * (r >> 2) + 4 * hi, 64);
        #pragma unroll
        for (int dt = 0; dt < 4; ++dt) of[dt][r] *= fr;
      }
    }

    u32x4 pa[4];
    #pragma unroll
    for (int g = 0; g < 4; ++g) {
      const float* sp = (g < 2) ? (const float*)&st0 : (const float*)&st1;
      const int o8 = (g & 1) * 8;
      u32 a0 = pk2(sp[o8 + 0], sp[o8 + 1]);
      u32 a1 = pk2(sp[o8 + 2], sp[o8 + 3]);
      u32 b0 = pk2(sp[o8 + 4], sp[o8 + 5]);
      u32 b1 = pk2(sp[o8 + 6], sp[o8 + 7]);
      u32 ta0 = __shfl_xor(a0, 32, 64);
      u32 ta1 = __shfl_xor(a1, 32, 64);
      u32 tb0 = __shfl_xor(b0, 32, 64);
      u32 tb1 = __shfl_xor(b1, 32, 64);
      pa[g][0] = hi ? tb0 : a0;
      pa[g][1] = hi ? tb1 : a1;
      pa[g][2] = hi ? b0  : ta0;
      pa[g][3] = hi ? b1  : ta1;
    }

    #pragma unroll
    for (int ks = 0; ks < 4; ++ks) {
      bf16x8 paf = __builtin_bit_cast(bf16x8, pa[ks]);
      #pragma unroll
      for (int dt = 0; dt < 4; ++dt)
        of[dt] = __builtin_amdgcn_mfma_f32_32x32x16_bf16(paf, vfr[dt][ks], of[dt], 0, 0, 0);
    }
  }

  if (w == 1) {
    #pragma unroll
    for (int dt = 0; dt < 4; ++dt)
      #pragma unroll
      for (int r = 0; r < 16; ++r)
        ofs[dt * 16 + r][lane] = of[dt][r];
    mls[0][lane] = m_run;
    mls[1][lane] = l_run;
  }
  __syncthreads();
  if (w == 0) {
    const float m1 = mls[0][l31];
    const float l1 = mls[1][l31];
    const float mt = fmaxf(m_run, m1);
    const float f0 = __builtin_amdgcn_exp2f(m_run - mt);
    const float f1 = __builtin_amdgcn_exp2f(m1 - mt);
    const float lt = l_run * f0 + l1 * f1;
    const float rl = 1.0f / lt;
    #pragma unroll
    for (int r = 0; r < 16; ++r) {
      int crow = (r & 3) + 8 * (r >> 2) + 4 * hi;
      float f0r = __shfl(f0, crow, 64);
      float f1r = __shfl(f1, crow, 64);
      float lr  = __shfl(rl, crow, 64);
      #pragma unroll
      for (int dt = 0; dt < 4; ++dt)
        out[((size_t)(bb * NT + q0 + crow)) * ND + dt * 32 + l31] =
            (of[dt][r] * f0r + ofs[dt * 16 + r][lane] * f1r) * lr;
    }
  }
}

extern "C" void kernel_launch(void* const* d_in, const int* in_sizes, int n_in,
                              void* d_out, int out_size, void* d_ws, size_t ws_size,
                              hipStream_t stream) {
  (void)in_sizes; (void)n_in; (void)out_size; (void)ws_size;
  const float* x  = (const float*)d_in[0];
  const float* Wq = (const float*)d_in[1];
  const float* Wk = (const float*)d_in[2];
  const float* Wv = (const float*)d_in[3];
  float* out = (float*)d_out;

  u16* qws = (u16*)d_ws;                                // frag-order q: 8 MB
  u16* kws = qws + (size_t)NB * NT * ND;                // frag-order k: 8 MB
  u16* vws = kws + (size_t)NB * NT * ND;                // frag-order v: 8 MB
  u16* wfs = vws + (size_t)NB * NT * ND;                // frag-order W: 768 KB

  wprep_k<<<dim3(12), dim3(256), 0, stream>>>(Wq, Wk, Wv, wfs);
  qkv_fused_k<<<dim3(1024), dim3(256), 0, stream>>>(x, wfs, qws, kws, vws);
  attn_fwd_k<<<dim3(1024), dim3(128), 0, stream>>>(qws, kws, vws, out);
}